// Round 1
// baseline (287.874 us; speedup 1.0000x reference)
//
#include <hip/hip_runtime.h>

#define N_NODES 100000
#define N_EDGES 1000000
#define D_FEAT  64

// ---------------------------------------------------------------------------
// Kernel 1: zero the output accumulator and the per-node in-degree counts.
// (harness poisons d_out / d_ws with 0xAA before timing; we must self-init)
// ---------------------------------------------------------------------------
__global__ void gcn_zero_kernel(float* __restrict__ out, float* __restrict__ counts) {
    int stride = gridDim.x * blockDim.x;
    int i = blockIdx.x * blockDim.x + threadIdx.x;
    const int total = N_NODES * D_FEAT;
    for (int idx = i; idx < total; idx += stride) out[idx] = 0.0f;
    for (int idx = i; idx < N_NODES; idx += stride) counts[idx] = 0.0f;
}

// ---------------------------------------------------------------------------
// Kernel 2: one 64-lane wave per edge.
//   lane l: out[dst[e]*64 + l] += emb[src[e]*64 + l]   (atomic)
//   lane 0: counts[dst[e]] += 1
// Embedding row read is a fully-coalesced 256B wave load; atomic writes are
// 64 contiguous dwords (one cache line pair) resolved at L2.
// ---------------------------------------------------------------------------
__global__ void gcn_scatter_kernel(const float* __restrict__ emb,
                                   const int* __restrict__ src,
                                   const int* __restrict__ dst,
                                   float* __restrict__ out,
                                   float* __restrict__ counts) {
    int gid  = blockIdx.x * blockDim.x + threadIdx.x;
    int edge = gid >> 6;
    int lane = gid & 63;
    if (edge >= N_EDGES) return;
    int s = src[edge];
    int d = dst[edge];
    float v = emb[(size_t)s * D_FEAT + lane];
    atomicAdd(&out[(size_t)d * D_FEAT + lane], v);
    if (lane == 0) atomicAdd(&counts[d], 1.0f);
}

// ---------------------------------------------------------------------------
// Kernel 3: out[n,f] /= max(counts[n], 1)
// ---------------------------------------------------------------------------
__global__ void gcn_norm_kernel(float* __restrict__ out,
                                const float* __restrict__ counts) {
    int i = blockIdx.x * blockDim.x + threadIdx.x;
    if (i >= N_NODES * D_FEAT) return;
    int n = i >> 6;  // D_FEAT == 64
    float c = counts[n];
    out[i] *= (1.0f / fmaxf(c, 1.0f));
}

extern "C" void kernel_launch(void* const* d_in, const int* in_sizes, int n_in,
                              void* d_out, int out_size, void* d_ws, size_t ws_size,
                              hipStream_t stream) {
    const float* emb = (const float*)d_in[0];
    const int*   src = (const int*)d_in[1];
    const int*   dst = (const int*)d_in[2];
    float* out    = (float*)d_out;
    float* counts = (float*)d_ws;   // N_NODES floats of scratch

    gcn_zero_kernel<<<2048, 256, 0, stream>>>(out, counts);

    // 64 threads per edge; 256-thread blocks -> 4 edges/block
    const int scatter_blocks = (N_EDGES * 64) / 256;  // 250000
    gcn_scatter_kernel<<<scatter_blocks, 256, 0, stream>>>(emb, src, dst, out, counts);

    const int norm_blocks = (N_NODES * D_FEAT + 255) / 256;
    gcn_norm_kernel<<<norm_blocks, 256, 0, stream>>>(out, counts);
}

// Round 2
// 197.874 us; speedup vs baseline: 1.4548x; 1.4548x over previous
//
#include <hip/hip_runtime.h>

#define N_NODES 100000
#define N_EDGES 1000000
#define D_FEAT  64

// ---------------------------------------------------------------------------
// Workspace layout (ints):
//   counts [N_NODES]   in-degree per node
//   base   [N_NODES]   start of node's bucket region
//   cur    [N_NODES]   scatter cursor (starts == base)
//   bucket [N_EDGES]   src ids grouped by dst
//   cursor [1]         global bump allocator
// ---------------------------------------------------------------------------
#define WS_COUNTS 0
#define WS_BASE   (N_NODES)
#define WS_CUR    (2 * N_NODES)
#define WS_BUCKET (3 * N_NODES)
#define WS_CURSOR (3 * N_NODES + N_EDGES)
#define WS_NEEDED ((size_t)(3 * N_NODES + N_EDGES + 1) * sizeof(int))

// ============================ CSR path =====================================

__global__ void csr_zero_kernel(int* __restrict__ ws) {
    int stride = gridDim.x * blockDim.x;
    for (int i = blockIdx.x * blockDim.x + threadIdx.x; i < N_NODES; i += stride)
        ws[WS_COUNTS + i] = 0;
    if (blockIdx.x == 0 && threadIdx.x == 0) ws[WS_CURSOR] = 0;
}

__global__ void csr_count_kernel(const int* __restrict__ dst, int* __restrict__ ws) {
    int stride = gridDim.x * blockDim.x;
    for (int e = blockIdx.x * blockDim.x + threadIdx.x; e < N_EDGES; e += stride)
        atomicAdd(&ws[WS_COUNTS + dst[e]], 1);
}

// Per-node base offsets: wave-level inclusive scan of counts, one global
// atomic per wave to allocate the wave's contiguous region.
__global__ void csr_base_kernel(int* __restrict__ ws) {
    int n    = blockIdx.x * blockDim.x + threadIdx.x;
    int lane = threadIdx.x & 63;
    int c = (n < N_NODES) ? ws[WS_COUNTS + n] : 0;
    int incl = c;
    #pragma unroll
    for (int off = 1; off < 64; off <<= 1) {
        int t = __shfl_up(incl, off);
        if (lane >= off) incl += t;
    }
    int total = __shfl(incl, 63);
    int wbase = 0;
    if (lane == 63) wbase = atomicAdd(&ws[WS_CURSOR], total);
    wbase = __shfl(wbase, 63);
    if (n < N_NODES) {
        int b = wbase + incl - c;
        ws[WS_BASE + n] = b;
        ws[WS_CUR + n]  = b;
    }
}

__global__ void csr_scatter_kernel(const int* __restrict__ src,
                                   const int* __restrict__ dst,
                                   int* __restrict__ ws) {
    int stride = gridDim.x * blockDim.x;
    for (int e = blockIdx.x * blockDim.x + threadIdx.x; e < N_EDGES; e += stride) {
        int d = dst[e];
        int slot = atomicAdd(&ws[WS_CUR + d], 1);
        ws[WS_BUCKET + slot] = src[e];
    }
}

// One 64-lane wave per node; lane == feature. Load up to 64 src-ids with one
// coalesced read, broadcast via shuffles, accumulate rows in registers,
// write the output row exactly once.
__global__ void csr_gather_kernel(const float* __restrict__ emb,
                                  const int* __restrict__ ws,
                                  float* __restrict__ out) {
    int wpb  = blockDim.x >> 6;
    int n    = blockIdx.x * wpb + (threadIdx.x >> 6);
    int lane = threadIdx.x & 63;
    if (n >= N_NODES) return;

    int deg = ws[WS_COUNTS + n];
    int b   = ws[WS_BASE + n];
    float acc = 0.0f;

    for (int chunk = 0; chunk < deg; chunk += 64) {
        int m = min(64, deg - chunk);
        int id = (lane < m) ? ws[WS_BUCKET + b + chunk + lane] : 0;
        int i = 0;
        for (; i + 4 <= m; i += 4) {
            int s0 = __shfl(id, i + 0);
            int s1 = __shfl(id, i + 1);
            int s2 = __shfl(id, i + 2);
            int s3 = __shfl(id, i + 3);
            float v0 = emb[(size_t)s0 * D_FEAT + lane];
            float v1 = emb[(size_t)s1 * D_FEAT + lane];
            float v2 = emb[(size_t)s2 * D_FEAT + lane];
            float v3 = emb[(size_t)s3 * D_FEAT + lane];
            acc += v0; acc += v1; acc += v2; acc += v3;
        }
        for (; i < m; ++i) {
            int s = __shfl(id, i);
            acc += emb[(size_t)s * D_FEAT + lane];
        }
    }
    float denom = (float)max(deg, 1);
    out[(size_t)n * D_FEAT + lane] = acc / denom;
}

// ======================= Fallback (R1 atomic path) =========================

__global__ void gcn_zero_kernel(float* __restrict__ out, float* __restrict__ counts) {
    int stride = gridDim.x * blockDim.x;
    int i = blockIdx.x * blockDim.x + threadIdx.x;
    const int total = N_NODES * D_FEAT;
    for (int idx = i; idx < total; idx += stride) out[idx] = 0.0f;
    for (int idx = i; idx < N_NODES; idx += stride) counts[idx] = 0.0f;
}

__global__ void gcn_scatter_kernel(const float* __restrict__ emb,
                                   const int* __restrict__ src,
                                   const int* __restrict__ dst,
                                   float* __restrict__ out,
                                   float* __restrict__ counts) {
    int gid  = blockIdx.x * blockDim.x + threadIdx.x;
    int edge = gid >> 6;
    int lane = gid & 63;
    if (edge >= N_EDGES) return;
    int s = src[edge];
    int d = dst[edge];
    float v = emb[(size_t)s * D_FEAT + lane];
    atomicAdd(&out[(size_t)d * D_FEAT + lane], v);
    if (lane == 0) atomicAdd(&counts[d], 1.0f);
}

__global__ void gcn_norm_kernel(float* __restrict__ out,
                                const float* __restrict__ counts) {
    int i = blockIdx.x * blockDim.x + threadIdx.x;
    if (i >= N_NODES * D_FEAT) return;
    int n = i >> 6;
    float c = counts[n];
    out[i] *= (1.0f / fmaxf(c, 1.0f));
}

// ===========================================================================

extern "C" void kernel_launch(void* const* d_in, const int* in_sizes, int n_in,
                              void* d_out, int out_size, void* d_ws, size_t ws_size,
                              hipStream_t stream) {
    const float* emb = (const float*)d_in[0];
    const int*   src = (const int*)d_in[1];
    const int*   dst = (const int*)d_in[2];
    float* out = (float*)d_out;

    if (ws_size >= WS_NEEDED) {
        int* ws = (int*)d_ws;
        csr_zero_kernel<<<256, 256, 0, stream>>>(ws);
        csr_count_kernel<<<2048, 256, 0, stream>>>(dst, ws);
        csr_base_kernel<<<(N_NODES + 255) / 256, 256, 0, stream>>>(ws);
        csr_scatter_kernel<<<2048, 256, 0, stream>>>(src, dst, ws);
        // 4 waves (nodes) per 256-thread block
        csr_gather_kernel<<<(N_NODES + 3) / 4, 256, 0, stream>>>(emb, ws, out);
    } else {
        float* counts = (float*)d_ws;
        gcn_zero_kernel<<<2048, 256, 0, stream>>>(out, counts);
        const int scatter_blocks = (N_EDGES * 64) / 256;
        gcn_scatter_kernel<<<scatter_blocks, 256, 0, stream>>>(emb, src, dst, out, counts);
        const int norm_blocks = (N_NODES * D_FEAT + 255) / 256;
        gcn_norm_kernel<<<norm_blocks, 256, 0, stream>>>(out, counts);
    }
}